// Round 7
// baseline (105.828 us; speedup 1.0000x reference)
//
#include <hip/hip_runtime.h>

typedef unsigned short u16;
typedef __attribute__((ext_vector_type(8))) short bf16x8;
typedef __attribute__((ext_vector_type(4))) float f32x4;

#define LSTR 520  // bf16 elems per LDS row: 512 + 8 pad

// ---------------- workspace layout (bytes) ----------------
#define WS_A0V     524288
#define WS_A0O     1048576
#define WS_QW      1572864
#define WS_QKV     2097152
#define WS_QUE     2621440
#define WS_A1V     3145728
#define WS_A1O     3670016
#define WS_VAL     4194304
#define WS_POL     4718592
#define WS_PWR     7882752
#define WS_KK      7915520
#define WS_VV      7981056
#define WS_A0VB    8574976
#define WS_A0OB    (WS_A0VB + 1024)
#define WS_QB      (WS_A0VB + 2048)
#define WS_QKVB    (WS_A0VB + 5120)
#define WS_QUEB    (WS_A0VB + 6144)
#define WS_A1VB    (WS_A0VB + 7168)
#define WS_A1OB    (WS_A0VB + 8192)
#define WS_VALB    (WS_A0VB + 9216)
#define WS_ANG     (WS_A0VB + 10240)
#define WS_ANB     (WS_A0VB + 11264)
#define WS_FNG     (WS_A0VB + 12288)
#define WS_FNB     (WS_A0VB + 13312)
#define WS_POLB    (WS_A0VB + 14336)

__device__ __forceinline__ float bf2f(u16 u) {
  union { unsigned int i; float f; } v; v.i = ((unsigned int)u) << 16; return v.f;
}
__device__ __forceinline__ u16 f2bf(float f) {
  union { float f; unsigned int i; } v; v.f = f;
  unsigned int r = v.i + 0x7fffu + ((v.i >> 16) & 1u);
  return (u16)(r >> 16);
}
__device__ __forceinline__ bf16x8 f8_to_bf(const float4 a, const float4 b) {
  u16 o[8] = {f2bf(a.x), f2bf(a.y), f2bf(a.z), f2bf(a.w),
              f2bf(b.x), f2bf(b.y), f2bf(b.z), f2bf(b.w)};
  return *(bf16x8*)o;
}
__device__ __forceinline__ f32x4 MFMA(bf16x8 a, bf16x8 b, f32x4 c) {
  return __builtin_amdgcn_mfma_f32_16x16x32_bf16(a, b, c, 0, 0, 0);
}
__device__ __forceinline__ void gl_lds16(const void* g, void* l) {
  __builtin_amdgcn_global_load_lds((const __attribute__((address_space(1))) void*)g,
                                   (__attribute__((address_space(3))) void*)l, 16, 0, 0);
}
// exec barrier with LDS visibility, WITHOUT vmcnt drain (keeps DMA streams alive)
__device__ __forceinline__ void LBAR() {
  asm volatile("s_waitcnt lgkmcnt(0)" ::: "memory");
  __builtin_amdgcn_sched_barrier(0);
  __builtin_amdgcn_s_barrier();
  __builtin_amdgcn_sched_barrier(0);
}

// ---------------- convert jobs (done inside k_prot/k_pkv) ----------------
// mode 0: plain f32->bf16. mode 1: per-wave-slice chunked for 512x512 W:
// elem (col,k): dst = (col>>5)*16384 + (k>>5)*1024 + ((k>>3)&3)*256 + (col&31)*8 + (k&7)
#define NJOBS 22
struct Job { const void* base; int eoff; int n; int dstoff; int mode; };
struct Jobs { Job j[NJOBS]; };

__device__ void conv_part(const Jobs& jobs, char* __restrict__ ws, int slice, int nslice) {
  const int tid = threadIdx.x;
  for (int jj = 0; jj < NJOBS; ++jj) {
    const Job jb = jobs.j[jj];
    u16* dst = (u16*)(ws + jb.dstoff);
    const float* src = (const float*)jb.base + jb.eoff;
    const int items = (jb.n + 7) >> 3;
    const int per = (items + nslice - 1) / nslice;
    const int lo = slice * per;
    const int hi = (lo + per < items) ? lo + per : items;
    for (int t = lo + tid; t < hi; t += 256) {
      const int i0 = t * 8;
      if (i0 + 8 <= jb.n) {
        const float4 a = *(const float4*)(src + i0);
        const float4 b = *(const float4*)(src + i0 + 4);
        u16 o[8] = {f2bf(a.x), f2bf(a.y), f2bf(a.z), f2bf(a.w),
                    f2bf(b.x), f2bf(b.y), f2bf(b.z), f2bf(b.w)};
        int off = i0;
        if (jb.mode == 1) {
          const int col = i0 >> 9, k0 = i0 & 511;
          off = (col >> 5) * 16384 + (k0 >> 5) * 1024 + ((k0 >> 3) & 3) * 256 + (col & 31) * 8;
        }
        *(uint4*)(dst + off) = *(uint4*)o;
      } else {
        for (int k = i0; k < jb.n; ++k) dst[k] = f2bf(src[k]);  // mode-0 small tails only
      }
    }
  }
}

// ---- per-wave DMA: 2KB chunk = 2 x 1KB; l is wave-uniform, src is per-lane
__device__ __forceinline__ void stage2k(const char* g, u16* l, int lane) {
  gl_lds16(g + lane * 16, l);
  gl_lds16(g + 1024 + lane * 16, l + 512);
}

// ---- per-wave streamed GEMM layer: wave wid owns cols [wid*32, wid*32+32).
// wb = this wave's private 4 x 2KB LDS ring. NO cross-wave barriers inside.
// Ledger (per wave): entering iter c, chunks c..c+3 in flight (8 instr).
// vmcnt(6) -> chunk c's 2 loads retired (in-order). ds_read slot c&3 + MFMA;
// lgkmcnt(0) -> reads landed; THEN restage slot c&3 with chunk c+4 (or next
// layer's chunk c-12). Tail (no next): vmcnt 6/4/2/0 at c=12..15.
__device__ __forceinline__ void gemm_pw(const u16* Xlds, const char* Wg, const char* Wn,
                                        u16* wb, const u16* bias, int wid, int lane,
                                        f32x4 acc[2]) {
  const int rc = lane & 15, kb = lane >> 4;
  acc[0] = (f32x4){0.f, 0.f, 0.f, 0.f};
  acc[1] = acc[0];
  const char* gw = Wg + wid * 32768;
  const char* gn = Wn ? Wn + wid * 32768 : nullptr;
#pragma unroll
  for (int c = 0; c < 16; ++c) {
    if (gn || c <= 12) asm volatile("s_waitcnt vmcnt(6)" ::: "memory");
    else if (c == 13) asm volatile("s_waitcnt vmcnt(4)" ::: "memory");
    else if (c == 14) asm volatile("s_waitcnt vmcnt(2)" ::: "memory");
    else asm volatile("s_waitcnt vmcnt(0)" ::: "memory");
    __builtin_amdgcn_sched_barrier(0);
    const u16* B = wb + (c & 3) * 1024;
    const bf16x8 a = *(const bf16x8*)&Xlds[rc * LSTR + c * 32 + kb * 8];
    const bf16x8 b0 = *(const bf16x8*)&B[kb * 256 + rc * 8];
    const bf16x8 b1 = *(const bf16x8*)&B[kb * 256 + (rc + 16) * 8];
    acc[0] = MFMA(a, b0, acc[0]);
    acc[1] = MFMA(a, b1, acc[1]);
    asm volatile("s_waitcnt lgkmcnt(0)" ::: "memory");  // slot's reads landed
    __builtin_amdgcn_sched_barrier(0);
    if (c < 12) stage2k(gw + (c + 4) * 2048, wb + (c & 3) * 1024, lane);
    else if (gn) stage2k(gn + (c - 12) * 2048, wb + (c & 3) * 1024, lane);
  }
#pragma unroll
  for (int nt = 0; nt < 2; ++nt) {
    const float bv = bf2f(bias[wid * 32 + nt * 16 + rc]);
#pragma unroll
    for (int r = 0; r < 4; ++r) acc[nt][r] += bv;
  }
}

__device__ __forceinline__ void store_bf(u16* dst, int wid, int lane, const f32x4 acc[2]) {
  const int cr = lane & 15, rb = (lane >> 4) * 4;
#pragma unroll
  for (int nt = 0; nt < 2; ++nt) {
    const int col = wid * 32 + nt * 16 + cr;
#pragma unroll
    for (int r = 0; r < 4; ++r) dst[(rb + r) * LSTR + col] = f2bf(acc[nt][r]);
  }
}

__device__ __forceinline__ void add_lds_bf(const u16* src, int wid, int lane, f32x4 acc[2]) {
  const int cr = lane & 15, rb = (lane >> 4) * 4;
#pragma unroll
  for (int nt = 0; nt < 2; ++nt) {
    const int col = wid * 32 + nt * 16 + cr;
#pragma unroll
    for (int r = 0; r < 4; ++r) acc[nt][r] += bf2f(src[(rb + r) * LSTR + col]);
  }
}

__device__ __forceinline__ void add_glb_f32(const float* g, int wid, int lane, f32x4 acc[2]) {
  const int cr = lane & 15, rb = (lane >> 4) * 4;
#pragma unroll
  for (int nt = 0; nt < 2; ++nt) {
    const int col = wid * 32 + nt * 16 + cr;
#pragma unroll
    for (int r = 0; r < 4; ++r) acc[nt][r] += g[(size_t)(rb + r) * 512 + col];
  }
}

__device__ __forceinline__ void layer_norm_bf(const u16* X, u16* dst, const u16* g,
                                              const u16* b, int wid, int lane) {
  float s = 0.f, q = 0.f;
#pragma unroll
  for (int c = lane; c < 512; c += 64) {
    const float v = bf2f(X[wid * LSTR + c]);
    s += v; q += v * v;
  }
#pragma unroll
  for (int m = 1; m < 64; m <<= 1) {
    s += __shfl_xor(s, m, 64);
    q += __shfl_xor(q, m, 64);
  }
  const float mu = s * (1.f / 512.f);
  const float rs = rsqrtf(q * (1.f / 512.f) - mu * mu + 1e-5f);
#pragma unroll
  for (int c = lane; c < 512; c += 64) {
    const float v = (bf2f(X[wid * LSTR + c]) - mu) * rs * bf2f(g[c]) + bf2f(b[c]);
    dst[wid * LSTR + c] = f2bf(v);
  }
}

// ---- k_prot: pwr (8 pieces x 4 rot) from RAW f32 inputs + convert share.
// 32 blocks = j(4) x colgrp(8), 256 thr.
__global__ __launch_bounds__(256) void k_prot(const float* __restrict__ pemb,
                                              const float* __restrict__ rot_w,
                                              const float* __restrict__ rot_b,
                                              u16* __restrict__ pwr_ws, Jobs jobs,
                                              char* __restrict__ ws) {
  __shared__ __align__(16) u16 A[16 * LSTR];
  const int tid = threadIdx.x, lane = tid & 63, wid = tid >> 6;
  const int j = blockIdx.x >> 3, g = blockIdx.x & 7;
  for (int idx = tid; idx < 16 * 64; idx += 256) {
    const int r = idx >> 6, c8 = (idx & 63) * 8;
    if (r < 8) {
      const float4 a = *(const float4*)(pemb + r * 512 + c8);
      const float4 b = *(const float4*)(pemb + r * 512 + c8 + 4);
      bf16x8 v = f8_to_bf(a, b);
      *(bf16x8*)&A[r * LSTR + c8] = v;
    } else {
      uint4 z = {0u, 0u, 0u, 0u};
      *(uint4*)&A[r * LSTR + c8] = z;
    }
  }
  __syncthreads();
  const int rc = lane & 15, kb = lane >> 4, rb = (lane >> 4) * 4;
  const int col = g * 64 + wid * 16 + rc;
  const bf16x8* ab = reinterpret_cast<const bf16x8*>(A) + rc * (LSTR / 8) + kb;
  const float* wf = rot_w + (size_t)(j * 512 + col) * 512 + kb * 8;
  f32x4 acc = (f32x4){0.f, 0.f, 0.f, 0.f};
#pragma unroll
  for (int ks = 0; ks < 16; ++ks) {
    const float4 w0 = *(const float4*)(wf + ks * 32);
    const float4 w1 = *(const float4*)(wf + ks * 32 + 4);
    acc = MFMA(ab[ks * 4], f8_to_bf(w0, w1), acc);
  }
  const float bv = rot_b[j * 512 + col];
#pragma unroll
  for (int r = 0; r < 4; ++r) {
    const int p = rb + r;
    if (p < 8) pwr_ws[(size_t)(p * 4 + j) * 512 + col] = f2bf(acc[r] + bv);
  }
  conv_part(jobs, ws, blockIdx.x, 64);
}

// ---- k_pkv: kk/vv[32][512] f32 from pwr + RAW f32 k_w/v_w + convert share.
// 32 blocks = t(2) x colgrp(16), 256 thr.
__global__ __launch_bounds__(256) void k_pkv(const u16* __restrict__ pwr_ws,
                                             const float* __restrict__ k_w,
                                             const float* __restrict__ k_b,
                                             const float* __restrict__ v_w,
                                             const float* __restrict__ v_b,
                                             float* __restrict__ kk_ws,
                                             float* __restrict__ vv_ws, Jobs jobs,
                                             char* __restrict__ ws) {
  __shared__ __align__(16) u16 A[32 * LSTR];
  const int tid = threadIdx.x, lane = tid & 63, wid = tid >> 6;
  const int t = blockIdx.x >> 4, g = blockIdx.x & 15;
  for (int idx = tid; idx < 32 * 64; idx += 256) {
    const int r = idx >> 6, c = idx & 63;
    *(uint4*)&A[r * LSTR + c * 8] = ((const uint4*)pwr_ws)[r * 64 + c];
  }
  __syncthreads();
  const float* W = t ? v_w : k_w;
  const float* Bb = t ? v_b : k_b;
  float* out = t ? vv_ws : kk_ws;
  const int rc = lane & 15, kb = lane >> 4, rb = (lane >> 4) * 4;
  const int rowt = wid >> 1;
  const int col = g * 32 + (wid & 1) * 16 + rc;
  const bf16x8* ab = reinterpret_cast<const bf16x8*>(A) + (rowt * 16 + rc) * (LSTR / 8) + kb;
  const float* wf = W + (size_t)col * 512 + kb * 8;
  f32x4 acc = (f32x4){0.f, 0.f, 0.f, 0.f};
#pragma unroll
  for (int ks = 0; ks < 16; ++ks) {
    const float4 w0 = *(const float4*)(wf + ks * 32);
    const float4 w1 = *(const float4*)(wf + ks * 32 + 4);
    acc = MFMA(ab[ks * 4], f8_to_bf(w0, w1), acc);
  }
  const float bv = Bb[col];
#pragma unroll
  for (int r = 0; r < 4; ++r)
    out[(size_t)(rowt * 16 + rb + r) * 512 + col] = acc[r] + bv;
  conv_part(jobs, ws, 32 + blockIdx.x, 64);
}

// ---- main fused chain: 32 blocks x 1024 threads (16 waves), 16 batch rows each.
// Per-wave decoupled weight streams; barriers only at layer boundaries.
__global__ __launch_bounds__(1024) void k_main(
    const float* __restrict__ state32, const float* __restrict__ mem32,
    const int* __restrict__ queue, const char* __restrict__ ws,
    const float* __restrict__ kk_ws, const float* __restrict__ vv_ws,
    float* __restrict__ out_pol, float* __restrict__ out_val) {
  __shared__ __align__(16) u16 X[16 * LSTR];
  __shared__ __align__(16) u16 WB[16 * 4096];  // 16 waves x (4 x 2KB ring)
  __shared__ int piece_s[16];
  __shared__ int qs_s;
  const int tid = threadIdx.x;
  const int lane = tid & 63, wid = tid >> 6;
  const int r0 = blockIdx.x * 16;
  u16* wb = &WB[wid * 4096];

  const u16* a0v_b = (const u16*)(ws + WS_A0VB);
  const u16* a0o_b = (const u16*)(ws + WS_A0OB);
  const u16* q_b   = (const u16*)(ws + WS_QB);
  const u16* qkv_b = (const u16*)(ws + WS_QKVB);
  const u16* que_b = (const u16*)(ws + WS_QUEB);
  const u16* a1v_b = (const u16*)(ws + WS_A1VB);
  const u16* a1o_b = (const u16*)(ws + WS_A1OB);
  const u16* val_b = (const u16*)(ws + WS_VALB);
  const u16* pol_w = (const u16*)(ws + WS_POL);  const u16* pol_b = (const u16*)(ws + WS_POLB);
  const u16* an_g = (const u16*)(ws + WS_ANG);   const u16* an_b = (const u16*)(ws + WS_ANB);
  const u16* fn_g = (const u16*)(ws + WS_FNG);   const u16* fn_b = (const u16*)(ws + WS_FNB);

  // prologue: start this wave's L1 stream (chunks 0..3)
  {
    const char* g0 = ws + WS_A0V + wid * 32768;
    stage2k(g0, wb, lane);
    stage2k(g0 + 2048, wb + 1024, lane);
    stage2k(g0 + 4096, wb + 2048, lane);
    stage2k(g0 + 6144, wb + 3072, lane);
  }
  // stage state rows (f32 -> bf16 LDS): 1024 threads x 8 elems = 16x512
  {
    const int r = tid >> 6, c8 = (tid & 63) * 8;
    const float* src = state32 + (size_t)(r0 + r) * 512 + c8;
    const float4 a = *(const float4*)src;
    const float4 b = *(const float4*)(src + 4);
    bf16x8 v = f8_to_bf(a, b);
    *(bf16x8*)&X[r * LSTR + c8] = v;
  }
  if (tid == 0) {  // int64-vs-int32 probe (int64: odd u32 words all zero)
    int odd = 0;
    for (int i = 1; i < 128; i += 2) odd += (queue[i] != 0);
    qs_s = (odd == 0) ? 2 : 1;
  }
  LBAR();  // X + qs_s visible
  if (tid < 16) piece_s[tid] = queue[(size_t)(r0 + tid) * 5 * qs_s] & 7;

  f32x4 acc[2], res[2];
  // L1: v0 = state @ a0v^T
  gemm_pw(X, ws + WS_A0V, ws + WS_A0O, wb, a0v_b, wid, lane, acc);
  LBAR();  // all waves done reading X
  store_bf(X, wid, lane, acc);
  LBAR();
  // L2: s0 = v0 @ a0o^T  (residual to regs)
  gemm_pw(X, ws + WS_A0O, ws + WS_QW, wb, a0o_b, wid, lane, acc);
  res[0] = acc[0]; res[1] = acc[1];
  LBAR();
  store_bf(X, wid, lane, acc);
  LBAR();
  // L3: qv = s0 @ q_w^T
  gemm_pw(X, ws + WS_QW, ws + WS_QKV, wb, q_b, wid, lane, acc);
  LBAR();
  store_bf(X, wid, lane, acc);
  LBAR();
  // 4-key attention, in place on X (thread (r,h) owns X[r][h*64..h*64+63])
  if (tid < 128) {
    const int r = tid >> 3, h = tid & 7;
    const int p = piece_s[r];
    const u16* qrow = &X[r * LSTR + h * 64];
    const float* kkp = kk_ws + (size_t)(p * 4) * 512 + h * 64;
    const float* vvp = vv_ws + (size_t)(p * 4) * 512 + h * 64;
    float lg[4];
#pragma unroll
    for (int jj = 0; jj < 4; ++jj) {
      float s = 0.f;
      const float* kj = kkp + jj * 512;
#pragma unroll
      for (int d = 0; d < 64; d += 4) {
        const float4 kv = *(const float4*)(kj + d);
        s += bf2f(qrow[d]) * kv.x + bf2f(qrow[d + 1]) * kv.y + bf2f(qrow[d + 2]) * kv.z +
             bf2f(qrow[d + 3]) * kv.w;
      }
      lg[jj] = s * 0.125f;
    }
    const float m = fmaxf(fmaxf(lg[0], lg[1]), fmaxf(lg[2], lg[3]));
    float e0 = __expf(lg[0] - m), e1 = __expf(lg[1] - m);
    float e2 = __expf(lg[2] - m), e3 = __expf(lg[3] - m);
    const float inv = 1.f / (e0 + e1 + e2 + e3);
    e0 *= inv; e1 *= inv; e2 *= inv; e3 *= inv;
    u16* orow = &X[r * LSTR + h * 64];
#pragma unroll
    for (int d = 0; d < 64; d += 4) {
      const float4 v0 = *(const float4*)(vvp + 0 * 512 + d);
      const float4 v1 = *(const float4*)(vvp + 1 * 512 + d);
      const float4 v2 = *(const float4*)(vvp + 2 * 512 + d);
      const float4 v3 = *(const float4*)(vvp + 3 * 512 + d);
      orow[d + 0] = f2bf(e0 * v0.x + e1 * v1.x + e2 * v2.x + e3 * v3.x);
      orow[d + 1] = f2bf(e0 * v0.y + e1 * v1.y + e2 * v2.y + e3 * v3.y);
      orow[d + 2] = f2bf(e0 * v0.z + e1 * v1.z + e2 * v2.z + e3 * v3.z);
      orow[d + 3] = f2bf(e0 * v0.w + e1 * v1.w + e2 * v2.w + e3 * v3.w);
    }
  }
  LBAR();
  // L4: x1 = s0(res) + attn @ qkv^T ; LN1 in place
  gemm_pw(X, ws + WS_QKV, ws + WS_QUE, wb, qkv_b, wid, lane, acc);
  acc[0] += res[0]; acc[1] += res[1];
  LBAR();
  store_bf(X, wid, lane, acc);
  LBAR();
  layer_norm_bf(X, X, an_g, an_b, wid, lane);
  LBAR();
  // L5: x2 = s1 + s1 @ que_w^T ; LN2 in place
  gemm_pw(X, ws + WS_QUE, ws + WS_A1V, wb, que_b, wid, lane, acc);
  add_lds_bf(X, wid, lane, acc);  // s1 still in X (pre-store), wave-own cols
  LBAR();
  store_bf(X, wid, lane, acc);
  LBAR();
  layer_norm_bf(X, X, fn_g, fn_b, wid, lane);
  LBAR();
  // L6: v1 = s2 @ a1v^T
  gemm_pw(X, ws + WS_A1V, ws + WS_A1O, wb, a1v_b, wid, lane, acc);
  LBAR();
  store_bf(X, wid, lane, acc);
  LBAR();
  // L7: xo = v1 @ a1o^T + memory
  gemm_pw(X, ws + WS_A1O, ws + WS_VAL, wb, a1o_b, wid, lane, acc);
  add_glb_f32(mem32 + (size_t)r0 * 512, wid, lane, acc);
  LBAR();
  store_bf(X, wid, lane, acc);
  LBAR();
  // L8: val = xo @ val_w^T -> out (f32); X keeps xo
  gemm_pw(X, ws + WS_VAL, nullptr, wb, val_b, wid, lane, acc);
  {
    const int cr = lane & 15, rb = (lane >> 4) * 4;
#pragma unroll
    for (int nt = 0; nt < 2; ++nt) {
      const int col = wid * 32 + nt * 16 + cr;
#pragma unroll
      for (int r = 0; r < 4; ++r) out_val[(size_t)(r0 + rb + r) * 512 + col] = acc[nt][r];
    }
  }
  // L9: pol = xo @ pol_w^T (10 cols), wave 0 only
  if (wid == 0) {
    const int rc = lane & 15, kb = lane >> 4;
    const int wrow = rc < 10 ? rc : 0;
    const bf16x8* ab = reinterpret_cast<const bf16x8*>(X) + rc * (LSTR / 8) + kb;
    const bf16x8* wbp = reinterpret_cast<const bf16x8*>(pol_w) + wrow * 64 + kb;
    f32x4 pa = (f32x4){0.f, 0.f, 0.f, 0.f};
#pragma unroll
    for (int ks = 0; ks < 16; ++ks) pa = MFMA(ab[ks * 4], wbp[ks * 4], pa);
    if (rc < 10) {
      const float bv = bf2f(pol_b[rc]);
      const int rb = (lane >> 4) * 4;
#pragma unroll
      for (int r = 0; r < 4; ++r) out_pol[(size_t)(r0 + rb + r) * 10 + rc] = pa[r] + bv;
    }
  }
}

extern "C" void kernel_launch(void* const* d_in, const int* in_sizes, int n_in, void* d_out,
                              int out_size, void* d_ws, size_t ws_size, hipStream_t stream) {
  (void)in_sizes; (void)n_in; (void)out_size; (void)ws_size;
  char* ws = (char*)d_ws;

  Jobs jobs;
  int ji = 0;
  auto add = [&](int idx, int eoff, int n, int off, int mode) {
    jobs.j[ji].base = d_in[idx]; jobs.j[ji].eoff = eoff; jobs.j[ji].n = n;
    jobs.j[ji].dstoff = off; jobs.j[ji].mode = mode; ++ji;
  };
  add(38, 524288, 262144, WS_A0V, 1);   // a0_in_w rows [1024:1536] (v-slice)
  add(40, 0, 262144, WS_A0O, 1);
  add(12, 0, 262144, WS_QW, 1);
  add(18, 0, 262144, WS_QKV, 1);
  add(20, 0, 262144, WS_QUE, 1);
  add(42, 524288, 262144, WS_A1V, 1);   // a1_in_w rows [1024:1536]
  add(44, 0, 262144, WS_A1O, 1);
  add(48, 0, 262144, WS_VAL, 1);
  add(46, 0, 5120, WS_POL, 0);
  add(39, 1024, 512, WS_A0VB, 0);
  add(41, 0, 512, WS_A0OB, 0);
  add(13, 0, 512, WS_QB, 0);
  add(19, 0, 512, WS_QKVB, 0);
  add(21, 0, 512, WS_QUEB, 0);
  add(43, 1024, 512, WS_A1VB, 0);
  add(45, 0, 512, WS_A1OB, 0);
  add(49, 0, 512, WS_VALB, 0);
  add(22, 0, 512, WS_ANG, 0);
  add(23, 0, 512, WS_ANB, 0);
  add(24, 0, 512, WS_FNG, 0);
  add(25, 0, 512, WS_FNB, 0);
  add(47, 0, 10, WS_POLB, 0);

  k_prot<<<dim3(32), dim3(256), 0, stream>>>((const float*)d_in[9], (const float*)d_in[10],
                                             (const float*)d_in[11], (u16*)(ws + WS_PWR),
                                             jobs, ws);
  k_pkv<<<dim3(32), dim3(256), 0, stream>>>((const u16*)(ws + WS_PWR), (const float*)d_in[14],
                                            (const float*)d_in[15], (const float*)d_in[16],
                                            (const float*)d_in[17], (float*)(ws + WS_KK),
                                            (float*)(ws + WS_VV), jobs, ws);

  float* out_pol = (float*)d_out;
  float* out_val = out_pol + 512 * 10;
  k_main<<<dim3(32), dim3(1024), 0, stream>>>(
      (const float*)d_in[3], (const float*)d_in[4], (const int*)d_in[1], (const char*)ws,
      (const float*)(ws + WS_KK), (const float*)(ws + WS_VV), out_pol, out_val);
}